// Round 11
// baseline (116.862 us; speedup 1.0000x reference)
//
#include <hip/hip_runtime.h>
#include <hip/hip_bf16.h>
#include <cfloat>
#include <cmath>

namespace {
constexpr int NB = 2;     // batch
constexpr int NN = 64;    // user inputs
constexpr int NC = 256;   // feature channels
constexpr int NK = 10;    // classes
constexpr float ALPHA = -1.0f / 18.0f;   // -0.5/sigma^2, sigma=3
constexpr int TMPL_FLOATS = 3 * NB * NC * NN;            // 384 KiB
// class-max partials: [tile(42)][q(4)][k(10)][px(256)]
constexpr int PART_FLOATS = 42 * 4 * NK * 256;           // 1.64 MiB
} // namespace

// Wave-uniform fp32-vs-bf16 sniff on x0's first 2KB (R1: fp32 confirmed;
// hedge kept). fp32 low halves ~uniform bits -> bf16-exp>=137 w.p. ~1.
__device__ __forceinline__ bool sniff_f32(const void* x0) {
  const ushort4 v = ((const ushort4*)x0)[threadIdx.x & 63];
  bool bad = (((v.x >> 7) & 0xFF) >= 137) | (((v.y >> 7) & 0xFF) >= 137) |
             (((v.z >> 7) & 0xFF) >= 137) | (((v.w >> 7) & 0xFF) >= 137);
  return __ballot(bad) != 0ULL;
}

__device__ __forceinline__ float ldf(const void* p, size_t i, bool f32) {
  return f32 ? ((const float*)p)[i]
             : __bfloat162float(((const __hip_bfloat16*)p)[i]);
}
__device__ __forceinline__ float bf2f(unsigned short u) {
  return __uint_as_float((unsigned)u << 16);   // bf16 -> fp32 exact
}

// tile (0..41) -> lvl, b, tl (256-px tile index within level/batch)
__device__ __forceinline__ void tile_decode(int tile, int& lvl, int& b, int& tl) {
  if (tile < 32)      { lvl = 0; b = tile >> 4; tl = tile & 15; }
  else if (tile < 40) { const int t = tile - 32; lvl = 1; b = t >> 2; tl = t & 3; }
  else                { lvl = 2; b = tile - 40; tl = 0; }
}

// ---------------------------------------------------------------------------
// Kernel 1 (unchanged, ~4us): per (level,b,n) template, thread = channel,
// per-thread Gaussian-window loop. Output [lvl][b][c][n].
// ---------------------------------------------------------------------------
__global__ __launch_bounds__(256) void tmpl_kernel(
    const void* __restrict__ x0, const void* __restrict__ x1,
    const void* __restrict__ x2, const void* __restrict__ centers,
    const int* __restrict__ idxp, const int* __restrict__ labels,
    float* __restrict__ tmpl_t) {
  const bool f32 = sniff_f32(x0);
  const int bx  = blockIdx.x;          // 384 blocks
  const int lvl = bx >> 7;
  const int b   = (bx >> 6) & 1;
  const int n   = bx & 63;
  const int W   = 64 >> lvl;
  const int HW  = W * W;
  const float s = (float)(8 << lvl);
  const void* feat = (lvl == 0) ? x0 : (lvl == 1) ? x1 : x2;

  __shared__ float ex[64], ey[64];
  __shared__ float sh_inv;
  __shared__ int   sh_win[4];

  const int t = threadIdx.x;
  const float cx = ldf(centers, (size_t)(b * NN + n) * 2 + 0, f32);
  const float cy = ldf(centers, (size_t)(b * NN + n) * 2 + 1, f32);

  if (t < W) {
    const float dx = (float)t * s + 0.5f - cx;
    const float dy = (float)t * s + 0.5f - cy;
    ex[t] = expf(ALPHA * dx * dx);
    ey[t] = expf(ALPHA * dy * dy);
  }
  __syncthreads();

  if (t == 0) {
    const bool i64 = (labels[1] == 0);            // int64 hedge
    const int  m   = b * NN + n;
    const int  iv  = i64 ? idxp[2 * m] : idxp[m];
    float Sx = 0.f, Sy = 0.f;
    for (int i = 0; i < W; ++i) { Sx += ex[i]; Sy += ey[i]; }
    sh_inv = (iv != -1) ? 1.0f / (Sx * Sy + 1e-8f) : 0.0f;
    int cs = (int)floorf((cx - 0.5f) / s + 0.5f); cs = min(max(cs, 0), W - 1);
    int rs = (int)floorf((cy - 0.5f) / s + 0.5f); rs = min(max(rs, 0), W - 1);
    const float tx = ex[cs] * 1e-7f, ty = ey[rs] * 1e-7f;
    int clo = cs, chi = cs, rlo = rs, rhi = rs;
    while (clo > 0     && ex[clo - 1] >= tx) --clo;
    while (chi < W - 1 && ex[chi + 1] >= tx) ++chi;
    while (rlo > 0     && ey[rlo - 1] >= ty) --rlo;
    while (rhi < W - 1 && ey[rhi + 1] >= ty) ++rhi;
    sh_win[0] = clo; sh_win[1] = chi; sh_win[2] = rlo; sh_win[3] = rhi;
  }
  __syncthreads();

  const float inv = sh_inv;
  const int clo = sh_win[0], chi = sh_win[1], rlo = sh_win[2], rhi = sh_win[3];
  const size_t cbase = (size_t)(b * NC + t) * HW;
  float acc = 0.f;
  for (int r = rlo; r <= rhi; ++r) {
    float rowa = 0.f;
    for (int c = clo; c <= chi; ++c)
      rowa += ex[c] * ldf(feat, cbase + r * W + c, f32);
    acc += ey[r] * rowa;
  }
  tmpl_t[(((size_t)lvl * NB + b) * NC + t) * NN + n] = acc * inv;
}

// ---------------------------------------------------------------------------
// Kernel 2 (v9): N-split. Block = (256-px tile, 16-n quarter); 168 blocks,
// 256 threads = 4 waves = 4 n each; lane = 4 px (float4 feat loads).
// Each b128 tmpl broadcast feeds 16 FMAs -> per-block ds reads 1024 (~5us/CU
// vs v5's 20). Full K=256 in-block -> class-max done here; partials are only
// [q][10][256px] (1.7 MB total vs R10's 21 MB — R10's regression source).
// q==0 blocks write the feat pass-through (wave wv handles c-quarter wv).
// ---------------------------------------------------------------------------
__global__ __launch_bounds__(256, 1) void cor_kernel(
    const void* __restrict__ x0, const void* __restrict__ x1,
    const void* __restrict__ x2, const int* __restrict__ labels,
    const float* __restrict__ tmpl_t, float* __restrict__ part,
    float* __restrict__ out) {
  const bool f32 = sniff_f32(x0);
  const int bx   = blockIdx.x;         // 168 = 42 tiles x 4 n-quarters
  const int tile = bx >> 2, q = bx & 3;
  int lvl, b, tl;
  tile_decode(tile, lvl, b, tl);
  const int W = 64 >> lvl, HW = W * W;
  const int lane = threadIdx.x & 63;
  const int wv   = __builtin_amdgcn_readfirstlane(threadIdx.x >> 6); // 0..3
  const int px   = tl * 256 + lane * 4;
  const void* feat = (lvl == 0) ? x0 : (lvl == 1) ? x1 : x2;
  const size_t base1 = (size_t)NB * (NC + NK) * 4096;
  const size_t base2 = base1 + (size_t)NB * (NC + NK) * 1024;
  const size_t lvl_base = (lvl == 0) ? 0 : (lvl == 1) ? base1 : base2;
  float* ob = out + lvl_base + (size_t)b * (NC + NK) * HW + px;

  __shared__ float tlds[NC][16];       // 16 KiB: block's tmpl slice [c][16n]
  __shared__ float kmb[4][NK][64][4];  // 40 KiB: per-wave class-max partials
  __shared__ int   lab[16];

  { // coalesced stage: rows [c][q*16..q*16+16) -> tlds, 1024 float4
    const float4* s4 =
        (const float4*)(tmpl_t + (size_t)(lvl * NB + b) * NC * NN);
    float4* d4 = (float4*)&tlds[0][0];
#pragma unroll
    for (int k = 0; k < 4; ++k) {
      const int m = threadIdx.x + k * 256;         // 0..1023
      d4[m] = s4[(size_t)(m >> 2) * 16 + q * 4 + (m & 3)];
    }
  }
  if (threadIdx.x < 16) {
    const bool i64 = (labels[1] == 0);             // int64 hedge
    const int  m   = b * NN + q * 16 + threadIdx.x;
    lab[threadIdx.x] = i64 ? labels[2 * m] : labels[m];
  }
  __syncthreads();

  float4 acc[4];                       // 4 n x 4 px
#pragma unroll
  for (int j = 0; j < 4; ++j) acc[j] = float4{0.f, 0.f, 0.f, 0.f};

  auto run = [&](auto loadf) {
    float4 fpre[4];                    // depth-4 float4 feat prefetch
#pragma unroll
    for (int k = 0; k < 4; ++k) fpre[k] = loadf(k);
#pragma unroll 4
    for (int c = 0; c < NC; ++c) {
      const float4 f = fpre[c & 3];
      fpre[c & 3] = loadf(min(c + 4, NC - 1));     // clamp: no OOB
      if (q == 0 && wv == (c >> 6))                // pass-through, once per c
        *(float4*)&ob[(size_t)c * HW] = f;
      const float4 tv = *(const float4*)&tlds[c][wv * 4];  // b128 broadcast
      acc[0].x += tv.x * f.x; acc[0].y += tv.x * f.y;
      acc[0].z += tv.x * f.z; acc[0].w += tv.x * f.w;
      acc[1].x += tv.y * f.x; acc[1].y += tv.y * f.y;
      acc[1].z += tv.y * f.z; acc[1].w += tv.y * f.w;
      acc[2].x += tv.z * f.x; acc[2].y += tv.z * f.y;
      acc[2].z += tv.z * f.z; acc[2].w += tv.z * f.w;
      acc[3].x += tv.w * f.x; acc[3].y += tv.w * f.y;
      acc[3].z += tv.w * f.z; acc[3].w += tv.w * f.w;
    }
  };
  if (f32) {
    const float* fp = (const float*)feat + (size_t)b * NC * HW + px;
    run([&](int c) { return *(const float4*)&fp[(size_t)c * HW]; });
  } else {
    const unsigned short* hp =
        (const unsigned short*)feat + (size_t)b * NC * HW + px;
    run([&](int c) {
      const ushort4 v = *(const ushort4*)&hp[(size_t)c * HW];
      return float4{bf2f(v.x), bf2f(v.y), bf2f(v.z), bf2f(v.w)};
    });
  }

  // per-wave class-max over its 4 n (invalid n have cor=0, still included)
  float4 km[NK];
#pragma unroll
  for (int k = 0; k < NK; ++k) km[k] = float4{-FLT_MAX, -FLT_MAX, -FLT_MAX, -FLT_MAX};
#pragma unroll
  for (int j = 0; j < 4; ++j) {
    const int L = lab[wv * 4 + j];
#pragma unroll
    for (int kk = 1; kk <= NK; ++kk)
      if (L == kk) {
        km[kk - 1].x = fmaxf(km[kk - 1].x, acc[j].x);
        km[kk - 1].y = fmaxf(km[kk - 1].y, acc[j].y);
        km[kk - 1].z = fmaxf(km[kk - 1].z, acc[j].z);
        km[kk - 1].w = fmaxf(km[kk - 1].w, acc[j].w);
      }
  }
#pragma unroll
  for (int k = 0; k < NK; ++k) *(float4*)&kmb[wv][k][lane][0] = km[k];
  __syncthreads();

  if (wv == 0) {                       // combine 4 waves -> block partial
    float* pp = part + ((size_t)(tile * 4 + q) * NK) * 256 + lane * 4;
#pragma unroll
    for (int k = 0; k < NK; ++k) {
      float4 m = *(float4*)&kmb[0][k][lane][0];
#pragma unroll
      for (int w = 1; w < 4; ++w) {
        const float4 o = *(float4*)&kmb[w][k][lane][0];
        m.x = fmaxf(m.x, o.x); m.y = fmaxf(m.y, o.y);
        m.z = fmaxf(m.z, o.z); m.w = fmaxf(m.w, o.w);
      }
      *(float4*)&pp[(size_t)k * 256] = m;
    }
  }
}

// ---------------------------------------------------------------------------
// Kernel 3: combine 4 n-quarter partials per tile, write 10 cor channels.
// 42 blocks x 256 threads, thread = px. 40 coalesced loads/thread.
// ---------------------------------------------------------------------------
__global__ __launch_bounds__(256) void combine_kernel(
    const float* __restrict__ part, float* __restrict__ out) {
  const int tile = blockIdx.x;         // 0..41
  int lvl, b, tl;
  tile_decode(tile, lvl, b, tl);
  const int W = 64 >> lvl, HW = W * W;
  const int px = tl * 256 + threadIdx.x;
  const size_t base1 = (size_t)NB * (NC + NK) * 4096;
  const size_t base2 = base1 + (size_t)NB * (NC + NK) * 1024;
  const size_t lvl_base = (lvl == 0) ? 0 : (lvl == 1) ? base1 : base2;
  float* ob = out + lvl_base + (size_t)b * (NC + NK) * HW + px;
  const float* pp = part + (size_t)tile * 4 * NK * 256 + threadIdx.x;

#pragma unroll
  for (int k = 0; k < NK; ++k) {
    float m = -FLT_MAX;
#pragma unroll
    for (int q = 0; q < 4; ++q)
      m = fmaxf(m, pp[(size_t)(q * NK + k) * 256]);
    ob[(size_t)(NC + k) * HW] = (m == -FLT_MAX) ? 0.f : m;   // absent -> 0
  }
}

extern "C" void kernel_launch(void* const* d_in, const int* in_sizes, int n_in,
                              void* d_out, int out_size, void* d_ws, size_t ws_size,
                              hipStream_t stream) {
  const void* x0 = d_in[0];
  const void* x1 = d_in[1];
  const void* x2 = d_in[2];
  const void* ce = d_in[3];
  const int* idxp   = (const int*)d_in[4];
  const int* labels = (const int*)d_in[5];
  float* tmpl = (float*)d_ws;                          // 384 KiB
  float* part = tmpl + TMPL_FLOATS;                    // 1.64 MiB partials
  float* out  = (float*)d_out;

  tmpl_kernel<<<3 * NB * NN, 256, 0, stream>>>(x0, x1, x2, ce, idxp, labels, tmpl);
  cor_kernel<<<168, 256, 0, stream>>>(x0, x1, x2, labels, tmpl, part, out);
  combine_kernel<<<42, 256, 0, stream>>>(part, out);
}

// Round 12
// 101.613 us; speedup vs baseline: 1.1501x; 1.1501x over previous
//
#include <hip/hip_runtime.h>
#include <hip/hip_bf16.h>
#include <cfloat>
#include <cmath>

namespace {
constexpr int NB = 2;     // batch
constexpr int NN = 64;    // user inputs
constexpr int NC = 256;   // feature channels
constexpr int NK = 10;    // classes
constexpr float ALPHA = -1.0f / 18.0f;   // -0.5/sigma^2, sigma=3
constexpr int TMPL_FLOATS = 3 * NB * NC * NN;            // 384 KiB
// class-max partials: [tile(42)][q(4)][k(10)][px(256)]
constexpr int PART_FLOATS = 42 * 4 * NK * 256;           // 1.64 MiB
} // namespace

// Wave-uniform fp32-vs-bf16 sniff on x0's first 2KB (R1: fp32 confirmed;
// hedge kept). fp32 low halves ~uniform bits -> bf16-exp>=137 w.p. ~1.
__device__ __forceinline__ bool sniff_f32(const void* x0) {
  const ushort4 v = ((const ushort4*)x0)[threadIdx.x & 63];
  bool bad = (((v.x >> 7) & 0xFF) >= 137) | (((v.y >> 7) & 0xFF) >= 137) |
             (((v.z >> 7) & 0xFF) >= 137) | (((v.w >> 7) & 0xFF) >= 137);
  return __ballot(bad) != 0ULL;
}

__device__ __forceinline__ float ldf(const void* p, size_t i, bool f32) {
  return f32 ? ((const float*)p)[i]
             : __bfloat162float(((const __hip_bfloat16*)p)[i]);
}
__device__ __forceinline__ float bf2f(unsigned short u) {
  return __uint_as_float((unsigned)u << 16);   // bf16 -> fp32 exact
}

// tile (0..41) -> lvl, b, tl (256-px tile index within level/batch)
__device__ __forceinline__ void tile_decode(int tile, int& lvl, int& b, int& tl) {
  if (tile < 32)      { lvl = 0; b = tile >> 4; tl = tile & 15; }
  else if (tile < 40) { const int t = tile - 32; lvl = 1; b = t >> 2; tl = t & 3; }
  else                { lvl = 2; b = tile - 40; tl = 0; }
}

// ---------------------------------------------------------------------------
// Kernel 1 (unchanged, ~4us): per (level,b,n) template, thread = channel,
// per-thread Gaussian-window loop. Output [lvl][b][c][n].
// ---------------------------------------------------------------------------
__global__ __launch_bounds__(256) void tmpl_kernel(
    const void* __restrict__ x0, const void* __restrict__ x1,
    const void* __restrict__ x2, const void* __restrict__ centers,
    const int* __restrict__ idxp, const int* __restrict__ labels,
    float* __restrict__ tmpl_t) {
  const bool f32 = sniff_f32(x0);
  const int bx  = blockIdx.x;          // 384 blocks
  const int lvl = bx >> 7;
  const int b   = (bx >> 6) & 1;
  const int n   = bx & 63;
  const int W   = 64 >> lvl;
  const int HW  = W * W;
  const float s = (float)(8 << lvl);
  const void* feat = (lvl == 0) ? x0 : (lvl == 1) ? x1 : x2;

  __shared__ float ex[64], ey[64];
  __shared__ float sh_inv;
  __shared__ int   sh_win[4];

  const int t = threadIdx.x;
  const float cx = ldf(centers, (size_t)(b * NN + n) * 2 + 0, f32);
  const float cy = ldf(centers, (size_t)(b * NN + n) * 2 + 1, f32);

  if (t < W) {
    const float dx = (float)t * s + 0.5f - cx;
    const float dy = (float)t * s + 0.5f - cy;
    ex[t] = expf(ALPHA * dx * dx);
    ey[t] = expf(ALPHA * dy * dy);
  }
  __syncthreads();

  if (t == 0) {
    const bool i64 = (labels[1] == 0);            // int64 hedge
    const int  m   = b * NN + n;
    const int  iv  = i64 ? idxp[2 * m] : idxp[m];
    float Sx = 0.f, Sy = 0.f;
    for (int i = 0; i < W; ++i) { Sx += ex[i]; Sy += ey[i]; }
    sh_inv = (iv != -1) ? 1.0f / (Sx * Sy + 1e-8f) : 0.0f;
    int cs = (int)floorf((cx - 0.5f) / s + 0.5f); cs = min(max(cs, 0), W - 1);
    int rs = (int)floorf((cy - 0.5f) / s + 0.5f); rs = min(max(rs, 0), W - 1);
    const float tx = ex[cs] * 1e-7f, ty = ey[rs] * 1e-7f;
    int clo = cs, chi = cs, rlo = rs, rhi = rs;
    while (clo > 0     && ex[clo - 1] >= tx) --clo;
    while (chi < W - 1 && ex[chi + 1] >= tx) ++chi;
    while (rlo > 0     && ey[rlo - 1] >= ty) --rlo;
    while (rhi < W - 1 && ey[rhi + 1] >= ty) ++rhi;
    sh_win[0] = clo; sh_win[1] = chi; sh_win[2] = rlo; sh_win[3] = rhi;
  }
  __syncthreads();

  const float inv = sh_inv;
  const int clo = sh_win[0], chi = sh_win[1], rlo = sh_win[2], rhi = sh_win[3];
  const size_t cbase = (size_t)(b * NC + t) * HW;
  float acc = 0.f;
  for (int r = rlo; r <= rhi; ++r) {
    float rowa = 0.f;
    for (int c = clo; c <= chi; ++c)
      rowa += ex[c] * ldf(feat, cbase + r * W + c, f32);
    acc += ey[r] * rowa;
  }
  tmpl_t[(((size_t)lvl * NB + b) * NC + t) * NN + n] = acc * inv;
}

// ---------------------------------------------------------------------------
// Kernel 2 (v10 hybrid): block = (256-px tile, 16-n quarter); 168 blocks,
// 1024 threads = 16 waves = 4 n-subs (4 n) x 4 c-quarters (64 c); lane = 4px.
// Fixes R11's two failure modes while keeping its wins:
//   occupancy: 2688 waves (R11: 672) -> latency hiding restored (R6 lesson);
//   chain: 64 c-iters/wave (R11: 256);
//   ds: 1024 broadcast b128/block (v5: 4096 -> 5us not 20us);
//   partials: class-max before global -> 1.7 MB (R10's 21 MB killed it).
// Epilogue: LDS cq-sum -> class-max over 16 n -> part_g; combine kernel last.
// ---------------------------------------------------------------------------
__global__ __launch_bounds__(1024, 1) void cor_kernel(
    const void* __restrict__ x0, const void* __restrict__ x1,
    const void* __restrict__ x2, const int* __restrict__ labels,
    const float* __restrict__ tmpl_t, float* __restrict__ part,
    float* __restrict__ out) {
  const bool f32 = sniff_f32(x0);
  const int bx   = blockIdx.x;         // 168 = 42 tiles x 4 n-quarters
  const int tile = bx >> 2, q = bx & 3;
  int lvl, b, tl;
  tile_decode(tile, lvl, b, tl);
  const int W = 64 >> lvl, HW = W * W;
  const int lane = threadIdx.x & 63;
  const int wv   = __builtin_amdgcn_readfirstlane(threadIdx.x >> 6); // 0..15
  const int nsub = wv & 3;             // 4 n: q*16 + nsub*4 + j
  const int cq   = wv >> 2;            // c-quarter [64cq, 64cq+64)
  const int px   = tl * 256 + lane * 4;
  const void* feat = (lvl == 0) ? x0 : (lvl == 1) ? x1 : x2;
  const size_t base1 = (size_t)NB * (NC + NK) * 4096;
  const size_t base2 = base1 + (size_t)NB * (NC + NK) * 1024;
  const size_t lvl_base = (lvl == 0) ? 0 : (lvl == 1) ? base1 : base2;
  float* ob = out + lvl_base + (size_t)b * (NC + NK) * HW + px;

  __shared__ float tlds[NC][16];       // 16 KiB: n-quarter tmpl slice [c][16n]
  __shared__ float pl[4][16][64][4];   // 64 KiB: [cq][n16][lane][px4]
  __shared__ float kmb[4][NK][64][4];  // 40 KiB: [nsub][k][lane][px4]
  __shared__ int   lab[16];

  { // stage tlds: 1024 float4, one per thread (R11-verified mapping)
    const float4* s4 =
        (const float4*)(tmpl_t + (size_t)(lvl * NB + b) * NC * NN);
    float4* d4 = (float4*)&tlds[0][0];
    const int m = threadIdx.x;
    d4[m] = s4[(size_t)(m >> 2) * 16 + q * 4 + (m & 3)];
  }
  if (threadIdx.x < 16) {
    const bool i64 = (labels[1] == 0);             // int64 hedge
    const int  m   = b * NN + q * 16 + threadIdx.x;
    lab[threadIdx.x] = i64 ? labels[2 * m] : labels[m];
  }
  __syncthreads();

  float4 acc[4];                       // 4 n x 4 px
#pragma unroll
  for (int j = 0; j < 4; ++j) acc[j] = float4{0.f, 0.f, 0.f, 0.f};

  const int c0 = cq * 64;
  auto run = [&](auto loadf) {
    float4 fpre[4];                    // depth-4 float4 feat prefetch
#pragma unroll
    for (int k = 0; k < 4; ++k) fpre[k] = loadf(c0 + k);
#pragma unroll 4
    for (int i = 0; i < 64; ++i) {
      const int c = c0 + i;
      const float4 f = fpre[i & 3];
      fpre[i & 3] = loadf(min(c + 4, NC - 1));     // clamp: no OOB
      if (q == 0 && nsub == 0)                     // pass-through: wave cq
        *(float4*)&ob[(size_t)c * HW] = f;         //   writes its own c-range
      const float4 tv = *(const float4*)&tlds[c][nsub * 4];  // b128 broadcast
      acc[0].x += tv.x * f.x; acc[0].y += tv.x * f.y;
      acc[0].z += tv.x * f.z; acc[0].w += tv.x * f.w;
      acc[1].x += tv.y * f.x; acc[1].y += tv.y * f.y;
      acc[1].z += tv.y * f.z; acc[1].w += tv.y * f.w;
      acc[2].x += tv.z * f.x; acc[2].y += tv.z * f.y;
      acc[2].z += tv.z * f.z; acc[2].w += tv.z * f.w;
      acc[3].x += tv.w * f.x; acc[3].y += tv.w * f.y;
      acc[3].z += tv.w * f.z; acc[3].w += tv.w * f.w;
    }
  };
  if (f32) {
    const float* fp = (const float*)feat + (size_t)b * NC * HW + px;
    run([&](int c) { return *(const float4*)&fp[(size_t)c * HW]; });
  } else {
    const unsigned short* hp =
        (const unsigned short*)feat + (size_t)b * NC * HW + px;
    run([&](int c) {
      const ushort4 v = *(const ushort4*)&hp[(size_t)c * HW];
      return float4{bf2f(v.x), bf2f(v.y), bf2f(v.z), bf2f(v.w)};
    });
  }

#pragma unroll
  for (int j = 0; j < 4; ++j)
    *(float4*)&pl[cq][nsub * 4 + j][lane][0] = acc[j];
  __syncthreads();

  // cq==0 waves (wv<4, nsub=wv): sum c-quarters, class-max over their 4 n
  if (cq == 0) {
    float4 km[NK];
#pragma unroll
    for (int k = 0; k < NK; ++k)
      km[k] = float4{-FLT_MAX, -FLT_MAX, -FLT_MAX, -FLT_MAX};
#pragma unroll
    for (int j = 0; j < 4; ++j) {
      const int n16 = nsub * 4 + j;
      const float4 p0 = *(float4*)&pl[0][n16][lane][0];
      const float4 p1 = *(float4*)&pl[1][n16][lane][0];
      const float4 p2 = *(float4*)&pl[2][n16][lane][0];
      const float4 p3 = *(float4*)&pl[3][n16][lane][0];
      const float4 tot = float4{p0.x + p1.x + p2.x + p3.x,
                                p0.y + p1.y + p2.y + p3.y,
                                p0.z + p1.z + p2.z + p3.z,
                                p0.w + p1.w + p2.w + p3.w};
      const int L = lab[n16];
#pragma unroll
      for (int kk = 1; kk <= NK; ++kk)
        if (L == kk) {
          km[kk - 1].x = fmaxf(km[kk - 1].x, tot.x);
          km[kk - 1].y = fmaxf(km[kk - 1].y, tot.y);
          km[kk - 1].z = fmaxf(km[kk - 1].z, tot.z);
          km[kk - 1].w = fmaxf(km[kk - 1].w, tot.w);
        }
    }
#pragma unroll
    for (int k = 0; k < NK; ++k) *(float4*)&kmb[nsub][k][lane][0] = km[k];
  }
  __syncthreads();

  if (wv == 0) {                       // block partial -> global (1.7 MB)
    float* pp = part + ((size_t)(tile * 4 + q) * NK) * 256 + lane * 4;
#pragma unroll
    for (int k = 0; k < NK; ++k) {
      float4 m = *(float4*)&kmb[0][k][lane][0];
#pragma unroll
      for (int w = 1; w < 4; ++w) {
        const float4 o = *(float4*)&kmb[w][k][lane][0];
        m.x = fmaxf(m.x, o.x); m.y = fmaxf(m.y, o.y);
        m.z = fmaxf(m.z, o.z); m.w = fmaxf(m.w, o.w);
      }
      *(float4*)&pp[(size_t)k * 256] = m;
    }
  }
}

// ---------------------------------------------------------------------------
// Kernel 3 (R11-verified): combine 4 n-quarter partials per tile, write the
// 10 cor channels. 42 blocks x 256 threads, thread = px.
// ---------------------------------------------------------------------------
__global__ __launch_bounds__(256) void combine_kernel(
    const float* __restrict__ part, float* __restrict__ out) {
  const int tile = blockIdx.x;         // 0..41
  int lvl, b, tl;
  tile_decode(tile, lvl, b, tl);
  const int W = 64 >> lvl, HW = W * W;
  const int px = tl * 256 + threadIdx.x;
  const size_t base1 = (size_t)NB * (NC + NK) * 4096;
  const size_t base2 = base1 + (size_t)NB * (NC + NK) * 1024;
  const size_t lvl_base = (lvl == 0) ? 0 : (lvl == 1) ? base1 : base2;
  float* ob = out + lvl_base + (size_t)b * (NC + NK) * HW + px;
  const float* pp = part + (size_t)tile * 4 * NK * 256 + threadIdx.x;

#pragma unroll
  for (int k = 0; k < NK; ++k) {
    float m = -FLT_MAX;
#pragma unroll
    for (int q = 0; q < 4; ++q)
      m = fmaxf(m, pp[(size_t)(q * NK + k) * 256]);
    ob[(size_t)(NC + k) * HW] = (m == -FLT_MAX) ? 0.f : m;   // absent -> 0
  }
}

extern "C" void kernel_launch(void* const* d_in, const int* in_sizes, int n_in,
                              void* d_out, int out_size, void* d_ws, size_t ws_size,
                              hipStream_t stream) {
  const void* x0 = d_in[0];
  const void* x1 = d_in[1];
  const void* x2 = d_in[2];
  const void* ce = d_in[3];
  const int* idxp   = (const int*)d_in[4];
  const int* labels = (const int*)d_in[5];
  float* tmpl = (float*)d_ws;                          // 384 KiB
  float* part = tmpl + TMPL_FLOATS;                    // 1.64 MiB partials
  float* out  = (float*)d_out;

  tmpl_kernel<<<3 * NB * NN, 256, 0, stream>>>(x0, x1, x2, ce, idxp, labels, tmpl);
  cor_kernel<<<168, 1024, 0, stream>>>(x0, x1, x2, labels, tmpl, part, out);
  combine_kernel<<<42, 256, 0, stream>>>(part, out);
}